// Round 1
// 556.398 us; speedup vs baseline: 1.0163x; 1.0163x over previous
//
#include <hip/hip_runtime.h>
#include <cstdint>

#define B_SZ 16
#define T_SZ 2048
#define H_SZ 1024
#define K_SZ 2048              // 2H
#define M_SZ (B_SZ * T_SZ)     // 32768

// fallback-path tile params (round-1 kernel, kept verbatim)
#define BM 128
#define BN 128
#define BK 64
#define LDK 72
#define KTILES (K_SZ / BK)     // 32

// fused-path tile params
#define FBM 64                 // rows per block
#define FBK 64                 // K per step

typedef _Float16 half8_t __attribute__((ext_vector_type(8)));
typedef _Float16 half4_t __attribute__((ext_vector_type(4)));
typedef float float4_t __attribute__((ext_vector_type(4)));

// ---------------------------------------------------------------------------
// Kernel 0b: W2 -> fp16, packed FRAGMENT-MAJOR for direct global->VGPR frags:
//   Bp[((nblk*64 + kblk)*64 + quad*16 + m16)*8 + j] = W[n][1024+k]
//   where n = nblk*16 + m16, k = kblk*32 + quad*8 + j.
//   A wave's B-frag load (fixed nblk,kblk; lane = quad*16+m16) is then one
//   fully-coalesced 1 KB global_load_dwordx4 — L2-resident (4 MB total).
// ---------------------------------------------------------------------------
__global__ __launch_bounds__(256) void cvt_w2_kernel(
    const float* __restrict__ W, _Float16* __restrict__ dst) {
    int idx8 = blockIdx.x * 256 + threadIdx.x;  // [0, 262144)
    int n = idx8 >> 8, k = (idx8 & 255) * 8;
    const float* src = W + (size_t)n * 3072 + H_SZ + k;
    float4_t a = *(const float4_t*)(src);
    float4_t b = *(const float4_t*)(src + 4);
    half8_t h;
    h[0] = (_Float16)a[0]; h[1] = (_Float16)a[1];
    h[2] = (_Float16)a[2]; h[3] = (_Float16)a[3];
    h[4] = (_Float16)b[0]; h[5] = (_Float16)b[1];
    h[6] = (_Float16)b[2]; h[7] = (_Float16)b[3];
    int nblk = n >> 4, m16 = n & 15;
    int kblk = k >> 5, quad = (k >> 3) & 3;
    size_t di = (((size_t)nblk * 64 + kblk) * 64 + quad * 16 + m16) * 8;
    *(half8_t*)(dst + di) = h;
}

// ---------------------------------------------------------------------------
// Kernel 1: hpart[b][h] = bias[h] + dot(hidden[b, :], W[h, 0:1024])
// ---------------------------------------------------------------------------
__global__ __launch_bounds__(256) void hpart_kernel(
    const float* __restrict__ hidden, const float* __restrict__ W,
    const float* __restrict__ bias, float* __restrict__ hpart) {
    int wave = (blockIdx.x * 256 + threadIdx.x) >> 6;  // [0, 16384)
    int lane = threadIdx.x & 63;
    int b = wave >> 10;
    int h = wave & 1023;
    const float* wrow = W + (size_t)h * 3072;
    const float* hrow = hidden + b * H_SZ;
    int k0 = lane * 16;
    float acc = 0.f;
#pragma unroll
    for (int j = 0; j < 4; ++j) {
        float4_t wv = *(const float4_t*)(wrow + k0 + j * 4);
        float4_t hv = *(const float4_t*)(hrow + k0 + j * 4);
        acc += wv[0] * hv[0] + wv[1] * hv[1] + wv[2] * hv[2] + wv[3] * hv[3];
    }
#pragma unroll
    for (int off = 32; off >= 1; off >>= 1) acc += __shfl_xor(acc, off, 64);
    if (lane == 0) hpart[b * H_SZ + h] = acc + bias[h];
}

// ---------------------------------------------------------------------------
// Kernel 2 (fused one-pass): BM=64 rows x full N=1024 per block.
//   - 1024 threads = 16 waves: wmg = w>>3 (m-group of 32 rows),
//     wn = w&7 (n-group of 128 cols). Per-wave acc = 2x8 float4 (64 VGPR).
//   - A (enc, fp32) is read ONCE from HBM: global->reg float4, cvt to fp16,
//     ds_write into XOR-swizzled double-buffered LDS tile (64x64, 8 KB each).
//     One barrier per K-step; prefetch load issued at loop top so HBM latency
//     hides under the 32-MFMA compute phase.
//   - B read directly global->VGPR from the packed fp16 table (L2-hot).
//   - Epilogue: tanh(acc+hp)*v, m16 shuffle-reduce, cross-wave LDS reduce,
//     final scores written -> (B,T). No partial slices.
// ---------------------------------------------------------------------------
__global__ __launch_bounds__(1024) void fused_attn_kernel(
    const float* __restrict__ enc, const _Float16* __restrict__ Bp,
    const float* __restrict__ hpart, const float* __restrict__ v,
    float* __restrict__ scores) {
    __shared__ __align__(16) _Float16 Af[2][FBM * FBK];  // 16 KB, swizzled
    __shared__ float hp_s[H_SZ];
    __shared__ float v_s[H_SZ];
    __shared__ float sred[8][FBM];

    const int tid = threadIdx.x;
    const int lane = tid & 63;
    const int w = tid >> 6;        // 0..15
    const int wn = w & 7;          // n-group: cols [wn*128, wn*128+128)
    const int wmg = w >> 3;        // m-group: rows [wmg*32, wmg*32+32)
    const int m16 = lane & 15, quad = lane >> 4;

    const int blockM = blockIdx.x;       // 0..511
    const int batch = blockM >> 5;       // 64 rows/block, 32 blocks/batch

    hp_s[tid] = hpart[batch * H_SZ + tid];
    v_s[tid] = v[tid];

    float4_t acc[2][8];
#pragma unroll
    for (int i = 0; i < 2; ++i)
#pragma unroll
        for (int j = 0; j < 8; ++j) acc[i][j] = (float4_t){0.f, 0.f, 0.f, 0.f};

    // ---- A staging addressing (fp32 global -> swizzled LDS fp16) ----
    const int arow = tid >> 4;           // 0..63
    const int acq = tid & 15;            // which float4 of the 64-float row
    const float* Aptr = enc + (size_t)(blockM * FBM + arow) * K_SZ + acq * 4;
    // 16B-slot XOR swizzle keyed by row&7; write is 8B (half4)
    const int wbyte = arow * 128 + ((((acq >> 1) ^ (arow & 7)) << 4) | ((acq & 1) * 8));
    char* AfB = (char*)Af;

    // ---- frag read byte offsets (same XOR on the read side) ----
    int fb[2][2];
#pragma unroll
    for (int tm = 0; tm < 2; ++tm) {
        int r = wmg * 32 + tm * 16 + m16;
#pragma unroll
        for (int ks = 0; ks < 2; ++ks)
            fb[tm][ks] = r * 128 + (((ks * 4 + quad) ^ (r & 7)) << 4);
    }

    // ---- B frag base (fragment-major packed table) ----
    const _Float16* Bfr = Bp + ((size_t)(wn * 8) * 64 * 64 + lane) * 8;
    // frag(tn, kblk) at Bfr + tn*32768 + kblk*512   (halves)

    // ---- prologue: stage K-tile 0 ----
    {
        float4_t av = *(const float4_t*)(Aptr);
        half4_t h;
        h[0] = (_Float16)av[0]; h[1] = (_Float16)av[1];
        h[2] = (_Float16)av[2]; h[3] = (_Float16)av[3];
        *(half4_t*)(AfB + wbyte) = h;
    }
    __syncthreads();

    int cur = 0;
    for (int kt = 0; kt < K_SZ / FBK; ++kt) {
        float4_t av;
        if (kt < K_SZ / FBK - 1) av = *(const float4_t*)(Aptr + (kt + 1) * FBK);
#pragma unroll
        for (int ks = 0; ks < 2; ++ks) {
            half8_t af0 = *(const half8_t*)(AfB + cur * 8192 + fb[0][ks]);
            half8_t af1 = *(const half8_t*)(AfB + cur * 8192 + fb[1][ks]);
            const _Float16* bk = Bfr + (size_t)(kt * 2 + ks) * 512;
#pragma unroll
            for (int g = 0; g < 2; ++g) {
                half8_t bf0 = *(const half8_t*)(bk + (size_t)(g * 4 + 0) * 32768);
                half8_t bf1 = *(const half8_t*)(bk + (size_t)(g * 4 + 1) * 32768);
                half8_t bf2 = *(const half8_t*)(bk + (size_t)(g * 4 + 2) * 32768);
                half8_t bf3 = *(const half8_t*)(bk + (size_t)(g * 4 + 3) * 32768);
                __builtin_amdgcn_s_setprio(1);
                acc[0][g * 4 + 0] = __builtin_amdgcn_mfma_f32_16x16x32_f16(af0, bf0, acc[0][g * 4 + 0], 0, 0, 0);
                acc[1][g * 4 + 0] = __builtin_amdgcn_mfma_f32_16x16x32_f16(af1, bf0, acc[1][g * 4 + 0], 0, 0, 0);
                acc[0][g * 4 + 1] = __builtin_amdgcn_mfma_f32_16x16x32_f16(af0, bf1, acc[0][g * 4 + 1], 0, 0, 0);
                acc[1][g * 4 + 1] = __builtin_amdgcn_mfma_f32_16x16x32_f16(af1, bf1, acc[1][g * 4 + 1], 0, 0, 0);
                acc[0][g * 4 + 2] = __builtin_amdgcn_mfma_f32_16x16x32_f16(af0, bf2, acc[0][g * 4 + 2], 0, 0, 0);
                acc[1][g * 4 + 2] = __builtin_amdgcn_mfma_f32_16x16x32_f16(af1, bf2, acc[1][g * 4 + 2], 0, 0, 0);
                acc[0][g * 4 + 3] = __builtin_amdgcn_mfma_f32_16x16x32_f16(af0, bf3, acc[0][g * 4 + 3], 0, 0, 0);
                acc[1][g * 4 + 3] = __builtin_amdgcn_mfma_f32_16x16x32_f16(af1, bf3, acc[1][g * 4 + 3], 0, 0, 0);
                __builtin_amdgcn_s_setprio(0);
            }
        }
        if (kt < K_SZ / FBK - 1) {
            half4_t h;
            h[0] = (_Float16)av[0]; h[1] = (_Float16)av[1];
            h[2] = (_Float16)av[2]; h[3] = (_Float16)av[3];
            *(half4_t*)(AfB + (cur ^ 1) * 8192 + wbyte) = h;
        }
        __syncthreads();
        cur ^= 1;
    }

    // ---- epilogue: tanh + v-dot, reduce over N ----
#pragma unroll
    for (int tm = 0; tm < 2; ++tm) {
        float s0 = 0.f, s1 = 0.f, s2 = 0.f, s3 = 0.f;
#pragma unroll
        for (int tn = 0; tn < 8; ++tn) {
            int nl = wn * 128 + tn * 16 + m16;
            float hpv = hp_s[nl];
            float vv = v_s[nl];
            s0 += tanhf(acc[tm][tn][0] + hpv) * vv;
            s1 += tanhf(acc[tm][tn][1] + hpv) * vv;
            s2 += tanhf(acc[tm][tn][2] + hpv) * vv;
            s3 += tanhf(acc[tm][tn][3] + hpv) * vv;
        }
#pragma unroll
        for (int off = 1; off < 16; off <<= 1) {
            s0 += __shfl_xor(s0, off, 64);
            s1 += __shfl_xor(s1, off, 64);
            s2 += __shfl_xor(s2, off, 64);
            s3 += __shfl_xor(s3, off, 64);
        }
        if (m16 == 0) {
            int rl = wmg * 32 + tm * 16 + quad * 4;
            sred[wn][rl + 0] = s0;
            sred[wn][rl + 1] = s1;
            sred[wn][rl + 2] = s2;
            sred[wn][rl + 3] = s3;
        }
    }
    __syncthreads();
    if (tid < FBM) {
        float t = 0.f;
#pragma unroll
        for (int i = 0; i < 8; ++i) t += sred[i][tid];
        scores[(size_t)blockM * FBM + tid] = t;
    }
}

// ---------------------------------------------------------------------------
// Kernel 3 (fast path): per-batch softmax over T=2048, single score slice.
// ---------------------------------------------------------------------------
__global__ __launch_bounds__(256) void softmax1_kernel(
    const float* __restrict__ scores, float* __restrict__ out) {
    __shared__ float red[256];
    const int b = blockIdx.x;
    const int tid = threadIdx.x;
    float sc[8];
    float mymax = -1e30f;
#pragma unroll
    for (int i = 0; i < 8; ++i) {
        float s = scores[b * T_SZ + i * 256 + tid];
        sc[i] = s;
        mymax = fmaxf(mymax, s);
    }
    red[tid] = mymax;
    __syncthreads();
    for (int off = 128; off >= 1; off >>= 1) {
        if (tid < off) red[tid] = fmaxf(red[tid], red[tid + off]);
        __syncthreads();
    }
    float mx = red[0];
    __syncthreads();
    float mysum = 0.f;
#pragma unroll
    for (int i = 0; i < 8; ++i) {
        sc[i] = expf(sc[i] - mx);
        mysum += sc[i];
    }
    red[tid] = mysum;
    __syncthreads();
    for (int off = 128; off >= 1; off >>= 1) {
        if (tid < off) red[tid] += red[tid + off];
        __syncthreads();
    }
    float inv = 1.0f / red[0];
#pragma unroll
    for (int i = 0; i < 8; ++i) out[b * T_SZ + i * 256 + tid] = sc[i] * inv;
}

// ---------------------------------------------------------------------------
// Fallback GEMM (round-1): fp32 loads with in-flight cvt (if ws too small)
// ---------------------------------------------------------------------------
__global__ __launch_bounds__(256, 2) void attn_gemm_kernel(
    const float* __restrict__ enc, const float* __restrict__ W,
    const float* __restrict__ hpart, const float* __restrict__ v,
    float* __restrict__ partial) {
    __shared__ _Float16 Afs[BM * LDK];
    __shared__ _Float16 Bfs[BN * LDK];
    __shared__ float hp_s[BN];
    __shared__ float v_s[BN];

    const int bidx = blockIdx.x;
    const int blockN = bidx & 7;
    const int blockM = bidx >> 3;
    const int tid = threadIdx.x;
    const int lane = tid & 63;
    const int w = tid >> 6;
    const int wm = w & 1, wn = w >> 1;
    const int m16 = lane & 15, quad = lane >> 4;

    const int n0 = blockN * BN;
    const int batch = blockM >> 4;

    if (tid < BN) {
        hp_s[tid] = hpart[batch * H_SZ + n0 + tid];
        v_s[tid] = v[n0 + tid];
    }

    float4_t acc[4][4];
#pragma unroll
    for (int i = 0; i < 4; ++i)
#pragma unroll
        for (int j = 0; j < 4; ++j) acc[i][j] = (float4_t){0.f, 0.f, 0.f, 0.f};

    const float* Abase = enc + (size_t)(blockM * BM) * K_SZ;
    const float* Bbase = W + (size_t)n0 * 3072 + H_SZ;

    for (int kt = 0; kt < KTILES; ++kt) {
        __syncthreads();
        const float* Asrc0 = Abase + kt * BK;
#pragma unroll
        for (int i = 0; i < 4; ++i) {
            int f8 = i * 256 + tid;
            int r = f8 >> 3, c8 = f8 & 7;
            const float* src = Asrc0 + (size_t)r * K_SZ + c8 * 8;
            float4_t lo = *(const float4_t*)(src);
            float4_t hi = *(const float4_t*)(src + 4);
            half8_t hv;
            hv[0] = (_Float16)lo[0]; hv[1] = (_Float16)lo[1];
            hv[2] = (_Float16)lo[2]; hv[3] = (_Float16)lo[3];
            hv[4] = (_Float16)hi[0]; hv[5] = (_Float16)hi[1];
            hv[6] = (_Float16)hi[2]; hv[7] = (_Float16)hi[3];
            *(half8_t*)&Afs[r * LDK + c8 * 8] = hv;
        }
        const float* Bsrc0 = Bbase + kt * BK;
#pragma unroll
        for (int i = 0; i < 4; ++i) {
            int f8 = i * 256 + tid;
            int r = f8 >> 3, c8 = f8 & 7;
            const float* src = Bsrc0 + (size_t)r * 3072 + c8 * 8;
            float4_t lo = *(const float4_t*)(src);
            float4_t hi = *(const float4_t*)(src + 4);
            half8_t hv;
            hv[0] = (_Float16)lo[0]; hv[1] = (_Float16)lo[1];
            hv[2] = (_Float16)lo[2]; hv[3] = (_Float16)lo[3];
            hv[4] = (_Float16)hi[0]; hv[5] = (_Float16)hi[1];
            hv[6] = (_Float16)hi[2]; hv[7] = (_Float16)hi[3];
            *(half8_t*)&Bfs[r * LDK + c8 * 8] = hv;
        }
        __syncthreads();
#pragma unroll
        for (int ks = 0; ks < 2; ++ks) {
            half8_t afrag[4], bfrag[4];
#pragma unroll
            for (int tm = 0; tm < 4; ++tm)
                afrag[tm] = *(const half8_t*)&Afs[(wm * 64 + tm * 16 + m16) * LDK + ks * 32 + quad * 8];
#pragma unroll
            for (int tn = 0; tn < 4; ++tn)
                bfrag[tn] = *(const half8_t*)&Bfs[(wn * 64 + tn * 16 + m16) * LDK + ks * 32 + quad * 8];
#pragma unroll
            for (int tm = 0; tm < 4; ++tm)
#pragma unroll
                for (int tn = 0; tn < 4; ++tn)
                    acc[tm][tn] = __builtin_amdgcn_mfma_f32_16x16x32_f16(
                        afrag[tm], bfrag[tn], acc[tm][tn], 0, 0, 0);
        }
    }

    const int slice = blockN * 2 + wn;
#pragma unroll
    for (int tm = 0; tm < 4; ++tm) {
        float s0 = 0.f, s1 = 0.f, s2 = 0.f, s3 = 0.f;
#pragma unroll
        for (int tn = 0; tn < 4; ++tn) {
            int nl = wn * 64 + tn * 16 + m16;
            float hpv = hp_s[nl];
            float vv = v_s[nl];
            s0 += tanhf(acc[tm][tn][0] + hpv) * vv;
            s1 += tanhf(acc[tm][tn][1] + hpv) * vv;
            s2 += tanhf(acc[tm][tn][2] + hpv) * vv;
            s3 += tanhf(acc[tm][tn][3] + hpv) * vv;
        }
#pragma unroll
        for (int off = 1; off < 16; off <<= 1) {
            s0 += __shfl_xor(s0, off, 64);
            s1 += __shfl_xor(s1, off, 64);
            s2 += __shfl_xor(s2, off, 64);
            s3 += __shfl_xor(s3, off, 64);
        }
        if (m16 == 0) {
            int gm = blockM * BM + wm * 64 + tm * 16 + quad * 4;
            float* dst = partial + (size_t)slice * M_SZ + gm;
            dst[0] = s0; dst[1] = s1; dst[2] = s2; dst[3] = s3;
        }
    }
}

// ---------------------------------------------------------------------------
// Fallback softmax: sums the 16 partial slices.
// ---------------------------------------------------------------------------
__global__ __launch_bounds__(256) void softmax_kernel(
    const float* __restrict__ partial, float* __restrict__ out) {
    __shared__ float red[256];
    const int b = blockIdx.x;
    const int tid = threadIdx.x;
    float sc[8];
    float mymax = -1e30f;
#pragma unroll
    for (int i = 0; i < 8; ++i) {
        int t = i * 256 + tid;
        float s = 0.f;
#pragma unroll
        for (int sl = 0; sl < 16; ++sl) s += partial[(size_t)sl * M_SZ + b * T_SZ + t];
        sc[i] = s;
        mymax = fmaxf(mymax, s);
    }
    red[tid] = mymax;
    __syncthreads();
    for (int off = 128; off >= 1; off >>= 1) {
        if (tid < off) red[tid] = fmaxf(red[tid], red[tid + off]);
        __syncthreads();
    }
    float mx = red[0];
    __syncthreads();
    float mysum = 0.f;
#pragma unroll
    for (int i = 0; i < 8; ++i) {
        sc[i] = expf(sc[i] - mx);
        mysum += sc[i];
    }
    red[tid] = mysum;
    __syncthreads();
    for (int off = 128; off >= 1; off >>= 1) {
        if (tid < off) red[tid] += red[tid + off];
        __syncthreads();
    }
    float inv = 1.0f / red[0];
#pragma unroll
    for (int i = 0; i < 8; ++i) out[b * T_SZ + i * 256 + tid] = sc[i] * inv;
}

// ---------------------------------------------------------------------------
extern "C" void kernel_launch(void* const* d_in, const int* in_sizes, int n_in,
                              void* d_out, int out_size, void* d_ws, size_t ws_size,
                              hipStream_t stream) {
    const float* hidden = (const float*)d_in[0];  // (16, 1024)
    const float* enc    = (const float*)d_in[1];  // (16, 2048, 2048)
    const float* W      = (const float*)d_in[2];  // (1024, 3072)
    const float* bias   = (const float*)d_in[3];  // (1024,)
    const float* v      = (const float*)d_in[4];  // (1024,)
    float* out = (float*)d_out;                   // (16, 1, 2048)

    // ws layout (fast): hpart 64 KB | scores 128 KB | w2h packed 4 MB
    float* hpart  = (float*)d_ws;
    float* scores = hpart + B_SZ * H_SZ;           // M_SZ floats
    _Float16* w2h = (_Float16*)(scores + M_SZ);
    const size_t need = (size_t)((char*)(w2h + (size_t)H_SZ * K_SZ) - (char*)d_ws);

    hipLaunchKernelGGL(hpart_kernel, dim3(4096), dim3(256), 0, stream,
                       hidden, W, bias, hpart);
    if (ws_size >= need) {
        hipLaunchKernelGGL(cvt_w2_kernel, dim3(1024), dim3(256), 0, stream, W, w2h);
        hipLaunchKernelGGL(fused_attn_kernel, dim3(M_SZ / FBM), dim3(1024), 0, stream,
                           enc, w2h, hpart, v, scores);
        hipLaunchKernelGGL(softmax1_kernel, dim3(B_SZ), dim3(256), 0, stream,
                           scores, out);
    } else {
        // fallback: ws layout: hpart | partial (16 slices, 2 MB)
        float* partial = scores;
        hipLaunchKernelGGL(attn_gemm_kernel, dim3(2048), dim3(256), 0, stream,
                           enc, W, hpart, v, partial);
        hipLaunchKernelGGL(softmax_kernel, dim3(B_SZ), dim3(256), 0, stream,
                           partial, out);
    }
}